// Round 4
// baseline (397.518 us; speedup 1.0000x reference)
//
#include <hip/hip_runtime.h>
#include <stdint.h>

#define T_SEQ   2048
#define HID     4096
#define NH      32
#define NKV     8
#define HD      128
#define QCOLS   6144
#define QK_SCALE 0.08838834764831845f  // 1/sqrt(128)

typedef _Float16 half_t;
typedef _Float16 half8 __attribute__((ext_vector_type(8)));
typedef _Float16 half4v __attribute__((ext_vector_type(4)));
typedef float    f32x4 __attribute__((ext_vector_type(4)));

typedef __attribute__((address_space(1))) const void cg_void;
typedef __attribute__((address_space(3))) void lds_void;

// ---------------- fused cast fp32 -> fp16 for all five inputs ----------------
__global__ __launch_bounds__(256) void cast_all_k(const float* __restrict__ X,
                                                  const float* __restrict__ Wq,
                                                  const float* __restrict__ Wk,
                                                  const float* __restrict__ Wv,
                                                  const float* __restrict__ Wo,
                                                  half_t* __restrict__ Xh,
                                                  half_t* __restrict__ Wqkvh,
                                                  half_t* __restrict__ Woh) {
  int i = blockIdx.x * 256 + threadIdx.x;   // float4 index, total 12582912
  const float* src; half_t* dst; int off;
  if (i < 2097152)      { src = X;  dst = Xh;               off = i; }
  else if (i < 6291456) { src = Wq; dst = Wqkvh;            off = i - 2097152; }
  else if (i < 7340032) { src = Wk; dst = Wqkvh + 16777216; off = i - 6291456; }
  else if (i < 8388608) { src = Wv; dst = Wqkvh + 20971520; off = i - 7340032; }
  else                  { src = Wo; dst = Woh;              off = i - 8388608; }
  f32x4 v = *(const f32x4*)(src + (size_t)off * 4);
  half4v o;
  o[0] = (half_t)v[0]; o[1] = (half_t)v[1]; o[2] = (half_t)v[2]; o[3] = (half_t)v[3];
  *(half4v*)(dst + (size_t)off * 4) = o;
}

// ---------------- RoPE cos/sin tables ----------------
__global__ __launch_bounds__(256) void rope_tables_k(float* __restrict__ cs) {
  int idx = blockIdx.x * 256 + threadIdx.x;  // 2048*64
  int t = idx >> 6, i = idx & 63;
  float inv = expf(-(float)i * 0.14391156831212787f);
  float a = (float)t * inv;
  cs[idx] = cosf(a);
  cs[131072 + idx] = sinf(a);
}

// ---------------- RoPE apply (in-place on fp16 QKV buffer) ----------------
__global__ __launch_bounds__(256) void rope_apply_k(half_t* __restrict__ QKV,
                                                    const float* __restrict__ cs) {
  int idx = blockIdx.x * 256 + threadIdx.x;  // 2048*40*64
  int i = idx & 63;
  int rem = idx >> 6;
  int head = rem % 40;
  int t = rem / 40;
  int colbase = (head < 32) ? head * HD : HID + (head - 32) * HD;
  size_t base = (size_t)t * QCOLS + colbase;
  float c = cs[t * 64 + i], s = cs[131072 + t * 64 + i];
  float x1 = (float)QKV[base + i];
  float x2 = (float)QKV[base + 64 + i];
  float o1 = x1 * c - x2 * s;
  float o2 = x1 * s + x2 * c;
  if (head < 32) { o1 *= QK_SCALE; o2 *= QK_SCALE; }
  QKV[base + i]      = (half_t)o1;
  QKV[base + 64 + i] = (half_t)o2;
}

// ---------------- V transpose: QKV V-slice [t][kh*128+d] -> Vt[kh][d][t] ----
__global__ __launch_bounds__(256) void transpose_v_k(const half_t* __restrict__ QKV,
                                                     half_t* __restrict__ Vt) {
  int idx = blockIdx.x * 256 + threadIdx.x;   // 8*128*256 = 262144
  int d  = idx & 127;
  int ts = (idx >> 7) & 255;
  int kh = idx >> 15;
  half8 o;
#pragma unroll
  for (int i = 0; i < 8; ++i)
    o[i] = QKV[(size_t)(ts * 8 + i) * QCOLS + HID + NKV * HD + kh * HD + d];
  *(half8*)&Vt[(size_t)kh * (HD * T_SEQ) + (size_t)d * T_SEQ + ts * 8] = o;
}

// ---------------- fp16 GEMM, 4-phase counted-vmcnt pipeline ----------------
// C[M][N] = A[M][K] * B[N][K]^T.  512 thr = 8 waves (2M x 4N), BK=64.
// A TRIPLE-buffered, B DOUBLE-buffered LDS. A(t+2) issued at phases 0-1,
// B(t+2) at phase 3 (into the buffer whose reads finished at phase 2).
// Tile-entry wait = s_waitcnt vmcnt(LA+LB) + raw s_barrier: the needed
// tile's loads are forced complete while the newest LA+LB stay in flight.
// XOR-(row&7) LDS swizzle (pre-swizzled global source, swizzled ds_read).
template <int BM, int BN, int OUT_HALF>
__global__ __launch_bounds__(512, 2) void gemm8p_k(const half_t* __restrict__ A,
                                                   const half_t* __restrict__ Bm,
                                                   void* __restrict__ Cout,
                                                   int M, int N, int K) {
  constexpr int MF = BM / 32;   // per-wave m fragments
  constexpr int NF = BN / 64;   // per-wave n fragments
  constexpr int MH = MF / 2;    // m frags per phase
  constexpr int LA = BM / 64;   // staging loads/thread, A tile
  constexpr int LB = BN / 64;
  constexpr int LA0 = LA / 2, LA1 = LA - LA0;
  constexpr int VM = LA + LB;   // steady-state entry vmcnt
  __shared__ half_t Al[3][BM * 64];
  __shared__ half_t Bl[2][BN * 64];

  const int nbm = M / BM;
  const int nwg = nbm * (N / BN);     // 256 for both instantiations
  const int bid = blockIdx.x;
  const int swz = (bid & 7) * (nwg >> 3) + (bid >> 3);  // bijective XCD swizzle
  const int brow = (swz % nbm) * BM;
  const int bcol = (swz / nbm) * BN;
  const int tid = threadIdx.x;
  const int lane = tid & 63, wid = tid >> 6;
  const int wr = wid >> 2, wc = wid & 3;
  const int lr = lane & 15, hi = lane >> 4;
  const int wrow = wr * (MF * 16), wcol = wc * (NF * 16);

  const half_t* Ab = A + (size_t)brow * K;
  const half_t* Bb = Bm + (size_t)bcol * K;

  f32x4 acc[MF][NF] = {};
  half8 afr[MH], bfr[NF];

#define STAGE_A(l, k0, buf) { \
    int c_ = (l) * 512 + tid; int r_ = c_ >> 3, s_ = c_ & 7; \
    __builtin_amdgcn_global_load_lds( \
      (cg_void*)(Ab + (size_t)r_ * K + (k0) + ((s_ ^ (r_ & 7)) * 8)), \
      (lds_void*)(&Al[buf][((l) * 512 + wid * 64) * 8]), 16, 0, 0); }
#define STAGE_B(l, k0, buf) { \
    int c_ = (l) * 512 + tid; int r_ = c_ >> 3, s_ = c_ & 7; \
    __builtin_amdgcn_global_load_lds( \
      (cg_void*)(Bb + (size_t)r_ * K + (k0) + ((s_ ^ (r_ & 7)) * 8)), \
      (lds_void*)(&Bl[buf][((l) * 512 + wid * 64) * 8]), 16, 0, 0); }
#define RD_A(i, mh, kk, buf) { \
    int row_ = wrow + ((mh) * MH + (i)) * 16 + lr; int ks_ = (kk) * 4 + hi; \
    afr[i] = *(const half8*)&Al[buf][row_ * 64 + ((ks_ ^ (row_ & 7)) * 8)]; }
#define RD_B(n, kk, buf) { \
    int row_ = wcol + (n) * 16 + lr; int ks_ = (kk) * 4 + hi; \
    bfr[n] = *(const half8*)&Bl[buf][row_ * 64 + ((ks_ ^ (row_ & 7)) * 8)]; }
#define MFMA_PH(mh) { \
    __builtin_amdgcn_s_setprio(1); \
    _Pragma("unroll") for (int i_ = 0; i_ < MH; ++i_) \
      _Pragma("unroll") for (int n_ = 0; n_ < NF; ++n_) \
        acc[(mh) * MH + i_][n_] = __builtin_amdgcn_mfma_f32_16x16x32_f16( \
            afr[i_], bfr[n_], acc[(mh) * MH + i_][n_], 0, 0, 0); \
    __builtin_amdgcn_s_setprio(0); }
#define BAR() { __builtin_amdgcn_s_barrier(); __builtin_amdgcn_sched_barrier(0); }

  const int NT = K / 64;
  // prologue: issue tiles 0 and 1 (A then B each), no wait yet
#pragma unroll
  for (int l_ = 0; l_ < LA; ++l_) STAGE_A(l_, 0, 0);
#pragma unroll
  for (int l_ = 0; l_ < LB; ++l_) STAGE_B(l_, 0, 0);
#pragma unroll
  for (int l_ = 0; l_ < LA; ++l_) STAGE_A(l_, 64, 1);
#pragma unroll
  for (int l_ = 0; l_ < LB; ++l_) STAGE_B(l_, 64, 1);

  int ab = 0, bb = 0;   // A buf = t%3, B buf = t%2
  for (int t = 0; t < NT; ++t) {
    // ---- tile entry: counted wait (tile t's loads complete; the LA+LB
    // loads issued during tile t-1 for tile t+1 stay in flight) ----
    if (t + 1 < NT) { asm volatile("s_waitcnt vmcnt(%0)" :: "n"(VM) : "memory"); }
    else            { asm volatile("s_waitcnt vmcnt(0)" ::: "memory"); }
    BAR();

    int a2 = ab + 2; if (a2 >= 3) a2 -= 3;
    const bool pf = (t + 2) < NT;
    const int kn = (t + 2) * 64;

    // phase 0: stage A(t+2) first half; B kk0 + A mh0,kk0; MFMA mh0
    if (pf) { _Pragma("unroll") for (int l_ = 0; l_ < LA0; ++l_) STAGE_A(l_, kn, a2); }
    _Pragma("unroll") for (int n_ = 0; n_ < NF; ++n_) RD_B(n_, 0, bb);
    _Pragma("unroll") for (int i_ = 0; i_ < MH; ++i_) RD_A(i_, 0, 0, ab);
    MFMA_PH(0);
    BAR();
    // phase 1: stage A(t+2) second half; A mh1,kk0 (reuse bfr); MFMA mh1
    if (pf) { _Pragma("unroll") for (int l_ = 0; l_ < LA1; ++l_) STAGE_A(LA0 + l_, kn, a2); }
    _Pragma("unroll") for (int i_ = 0; i_ < MH; ++i_) RD_A(i_, 1, 0, ab);
    MFMA_PH(1);
    BAR();
    // phase 2: B kk1 + A mh1,kk1; MFMA mh1  (B LDS reads finish here)
    _Pragma("unroll") for (int n_ = 0; n_ < NF; ++n_) RD_B(n_, 1, bb);
    _Pragma("unroll") for (int i_ = 0; i_ < MH; ++i_) RD_A(i_, 1, 1, ab);
    MFMA_PH(1);
    BAR();
    // phase 3: stage B(t+2) into Bl[bb] (dead after phase 2); A mh0,kk1; MFMA mh0
    if (pf) { _Pragma("unroll") for (int l_ = 0; l_ < LB; ++l_) STAGE_B(l_, kn, bb); }
    _Pragma("unroll") for (int i_ = 0; i_ < MH; ++i_) RD_A(i_, 0, 1, ab);
    MFMA_PH(0);
    // next tile's entry wait+barrier separates these reads from refills

    ab = (ab + 1 == 3) ? 0 : ab + 1;
    bb ^= 1;
  }

#undef STAGE_A
#undef STAGE_B
#undef RD_A
#undef RD_B
#undef MFMA_PH
#undef BAR

#pragma unroll
  for (int m = 0; m < MF; ++m)
#pragma unroll
    for (int n = 0; n < NF; ++n)
#pragma unroll
      for (int r = 0; r < 4; ++r) {
        int row = brow + wrow + m * 16 + hi * 4 + r;
        int col = bcol + wcol + n * 16 + lr;
        float v = acc[m][n][r];
        if (OUT_HALF) ((half_t*)Cout)[(size_t)row * N + col] = (half_t)v;
        else          ((float*)Cout)[(size_t)row * N + col] = v;
      }
}

// ---------------- fused causal GQA flash attention (unchanged) ----------------
__global__ __launch_bounds__(256) void attn_k(const half_t* __restrict__ QKV,
                                              const half_t* __restrict__ Vt,
                                              half_t* __restrict__ Ob) {
  const int bid = blockIdx.x;
  const int qb = 31 - (bid >> 5);
  const int h  = bid & 31;
  const int kh = h >> 2;
  const int tid = threadIdx.x;
  const int lane = tid & 63;
  const int w = tid >> 6;
  const int lr = lane & 15, hi = lane >> 4;
  const int qrow = qb * 64 + w * 16;

  __shared__ half_t Klds[64 * 128];
  __shared__ half_t Vlds[128 * 64];
  __shared__ half_t Plds[4 * 16 * 72];

  const half_t* Qp  = QKV + h * HD;
  const half_t* Kp  = QKV + HID + kh * HD;
  const half_t* Vtp = Vt + (size_t)kh * (HD * T_SEQ);

  half8 qf[4];
#pragma unroll
  for (int kk = 0; kk < 4; ++kk)
    qf[kk] = *(const half8*)&Qp[(size_t)(qrow + lr) * QCOLS + kk * 32 + hi * 8];

  f32x4 acc[8] = {};
  float mrow[4], lrow[4];
#pragma unroll
  for (int r = 0; r < 4; ++r) { mrow[r] = -1e30f; lrow[r] = 0.0f; }

  half_t* Pw = &Plds[w * (16 * 72)];
  const int nt = qb + 1;
  for (int t = 0; t < nt; ++t) {
    const int kv0 = t * 64;
#pragma unroll
    for (int c = 0; c < 4; ++c) {
      int chunk = c * 256 + tid;
      int r = chunk >> 4, s = chunk & 15;
      int cc = (s & 8) | ((s ^ r) & 7);
      __builtin_amdgcn_global_load_lds(
          (cg_void*)(Kp + (size_t)(kv0 + r) * QCOLS + cc * 8),
          (lds_void*)(&Klds[(c * 256 + w * 64) * 8]), 16, 0, 0);
    }
#pragma unroll
    for (int c = 0; c < 4; ++c) {
      int chunk = c * 256 + tid;
      int r = chunk >> 3, s = chunk & 7;
      int cc = (s ^ r) & 7;
      __builtin_amdgcn_global_load_lds(
          (cg_void*)(Vtp + (size_t)r * T_SEQ + kv0 + cc * 8),
          (lds_void*)(&Vlds[(c * 256 + w * 64) * 8]), 16, 0, 0);
    }
    __syncthreads();

    f32x4 s[4] = {};
#pragma unroll
    for (int jt = 0; jt < 4; ++jt)
#pragma unroll
      for (int kk = 0; kk < 4; ++kk) {
        int srow = jt * 16 + lr;
        int sl = kk * 4 + hi;
        int c = (sl & 8) | ((sl ^ srow) & 7);
        half8 kf = *(const half8*)&Klds[srow * 128 + c * 8];
        s[jt] = __builtin_amdgcn_mfma_f32_16x16x32_f16(qf[kk], kf, s[jt], 0, 0, 0);
      }

    if (t == qb) {
#pragma unroll
      for (int jt = 0; jt < 4; ++jt)
#pragma unroll
        for (int r = 0; r < 4; ++r) {
          int ig = qrow + hi * 4 + r;
          int jg = kv0 + jt * 16 + lr;
          if (jg > ig) s[jt][r] = -1e30f;
        }
    }

    float mx[4], scl[4], ls[4];
#pragma unroll
    for (int r = 0; r < 4; ++r)
      mx[r] = fmaxf(fmaxf(s[0][r], s[1][r]), fmaxf(s[2][r], s[3][r]));
#pragma unroll
    for (int off = 1; off < 16; off <<= 1)
#pragma unroll
      for (int r = 0; r < 4; ++r)
        mx[r] = fmaxf(mx[r], __shfl_xor(mx[r], off, 64));
#pragma unroll
    for (int r = 0; r < 4; ++r) {
      float mn = fmaxf(mrow[r], mx[r]);
      scl[r] = __expf(mrow[r] - mn);
      mrow[r] = mn;
      ls[r] = 0.0f;
#pragma unroll
      for (int jt = 0; jt < 4; ++jt) {
        s[jt][r] = __expf(s[jt][r] - mn);
        ls[r] += s[jt][r];
      }
    }
#pragma unroll
    for (int off = 1; off < 16; off <<= 1)
#pragma unroll
      for (int r = 0; r < 4; ++r)
        ls[r] += __shfl_xor(ls[r], off, 64);
#pragma unroll
    for (int r = 0; r < 4; ++r) lrow[r] = lrow[r] * scl[r] + ls[r];
#pragma unroll
    for (int g = 0; g < 8; ++g)
#pragma unroll
      for (int r = 0; r < 4; ++r) acc[g][r] *= scl[r];

#pragma unroll
    for (int jt = 0; jt < 4; ++jt)
#pragma unroll
      for (int r = 0; r < 4; ++r)
        Pw[(hi * 4 + r) * 72 + jt * 16 + lr] = (half_t)s[jt][r];
    half8 pf[2];
#pragma unroll
    for (int jt = 0; jt < 2; ++jt)
      pf[jt] = *(const half8*)&Pw[lr * 72 + jt * 32 + hi * 8];

#pragma unroll
    for (int g = 0; g < 8; ++g)
#pragma unroll
      for (int jt = 0; jt < 2; ++jt) {
        int vrow = g * 16 + lr;
        int sl = jt * 4 + hi;
        int c = (sl ^ vrow) & 7;
        half8 vf = *(const half8*)&Vlds[vrow * 64 + c * 8];
        acc[g] = __builtin_amdgcn_mfma_f32_16x16x32_f16(pf[jt], vf, acc[g], 0, 0, 0);
      }
    __syncthreads();
  }

#pragma unroll
  for (int g = 0; g < 8; ++g)
#pragma unroll
    for (int r = 0; r < 4; ++r) {
      int row = qrow + hi * 4 + r;
      int col = h * HD + g * 16 + lr;
      Ob[(size_t)row * HID + col] = (half_t)(acc[g][r] / lrow[r]);
    }
}

// ---------------- launch ----------------
extern "C" void kernel_launch(void* const* d_in, const int* in_sizes, int n_in,
                              void* d_out, int out_size, void* d_ws, size_t ws_size,
                              hipStream_t stream) {
  const float* hs = (const float*)d_in[0];
  const float* Wq = (const float*)d_in[1];
  const float* Wk = (const float*)d_in[2];
  const float* Wv = (const float*)d_in[3];
  const float* Wo = (const float*)d_in[4];
  float* out = (float*)d_out;

  char* ws = (char*)d_ws;
  half_t* Xh    = (half_t*)(ws + 0);           // 16 MB (dead after gemm1)
  half_t* Vt    = (half_t*)(ws + 0);           // 4 MB, reuses Xh region
  half_t* Wqkvh = (half_t*)(ws + 16777216);    // 48 MB [6144][4096]
  half_t* Woh   = (half_t*)(ws + 67108864);    // 32 MB
  half_t* QKV   = (half_t*)(ws + 100663296);   // 24 MB [2048][6144]
  half_t* attnh = (half_t*)(ws + 125829120);   // 16 MB [2048][4096]
  float*  cs    = (float*)(ws + 142606336);    // 1 MB cos|sin tables
  if (ws_size < 143654912ull) return;

  cast_all_k<<<49152, 256, 0, stream>>>(hs, Wq, Wk, Wv, Wo, Xh, Wqkvh, Woh);
  rope_tables_k<<<512, 256, 0, stream>>>(cs);

  gemm8p_k<256, 192, 1><<<256, 512, 0, stream>>>(Xh, Wqkvh, (void*)QKV, 2048, 6144, 4096);
  rope_apply_k<<<20480, 256, 0, stream>>>(QKV, cs);
  transpose_v_k<<<1024, 256, 0, stream>>>(QKV, Vt);
  attn_k<<<1024, 256, 0, stream>>>(QKV, Vt, attnh);
  gemm8p_k<128, 256, 0><<<256, 512, 0, stream>>>(attnh, Woh, (void*)out, 2048, 4096, 4096);
}

// Round 5
// 336.190 us; speedup vs baseline: 1.1824x; 1.1824x over previous
//
#include <hip/hip_runtime.h>
#include <stdint.h>

#define T_SEQ   2048
#define HID     4096
#define NH      32
#define NKV     8
#define HD      128
#define QCOLS   6144
#define QK_SCALE 0.08838834764831845f  // 1/sqrt(128)

typedef _Float16 half_t;
typedef _Float16 half8 __attribute__((ext_vector_type(8)));
typedef _Float16 half4v __attribute__((ext_vector_type(4)));
typedef float    f32x4 __attribute__((ext_vector_type(4)));

typedef __attribute__((address_space(1))) const void cg_void;
typedef __attribute__((address_space(3))) void lds_void;

// ---------------- fused cast fp32 -> fp16 for all five inputs ----------------
__global__ __launch_bounds__(256) void cast_all_k(const float* __restrict__ X,
                                                  const float* __restrict__ Wq,
                                                  const float* __restrict__ Wk,
                                                  const float* __restrict__ Wv,
                                                  const float* __restrict__ Wo,
                                                  half_t* __restrict__ Xh,
                                                  half_t* __restrict__ Wqkvh,
                                                  half_t* __restrict__ Woh) {
  int i = blockIdx.x * 256 + threadIdx.x;   // float4 index, total 12582912
  const float* src; half_t* dst; int off;
  if (i < 2097152)      { src = X;  dst = Xh;               off = i; }
  else if (i < 6291456) { src = Wq; dst = Wqkvh;            off = i - 2097152; }
  else if (i < 7340032) { src = Wk; dst = Wqkvh + 16777216; off = i - 6291456; }
  else if (i < 8388608) { src = Wv; dst = Wqkvh + 20971520; off = i - 7340032; }
  else                  { src = Wo; dst = Woh;              off = i - 8388608; }
  f32x4 v = *(const f32x4*)(src + (size_t)off * 4);
  half4v o;
  o[0] = (half_t)v[0]; o[1] = (half_t)v[1]; o[2] = (half_t)v[2]; o[3] = (half_t)v[3];
  *(half4v*)(dst + (size_t)off * 4) = o;
}

// ---------------- RoPE cos/sin tables ----------------
__global__ __launch_bounds__(256) void rope_tables_k(float* __restrict__ cs) {
  int idx = blockIdx.x * 256 + threadIdx.x;  // 2048*64
  int t = idx >> 6, i = idx & 63;
  float inv = expf(-(float)i * 0.14391156831212787f);
  float a = (float)t * inv;
  cs[idx] = cosf(a);
  cs[131072 + idx] = sinf(a);
}

// ---------------- RoPE apply (in-place on fp16 QKV buffer) ----------------
__global__ __launch_bounds__(256) void rope_apply_k(half_t* __restrict__ QKV,
                                                    const float* __restrict__ cs) {
  int idx = blockIdx.x * 256 + threadIdx.x;  // 2048*40*64
  int i = idx & 63;
  int rem = idx >> 6;
  int head = rem % 40;
  int t = rem / 40;
  int colbase = (head < 32) ? head * HD : HID + (head - 32) * HD;
  size_t base = (size_t)t * QCOLS + colbase;
  float c = cs[t * 64 + i], s = cs[131072 + t * 64 + i];
  float x1 = (float)QKV[base + i];
  float x2 = (float)QKV[base + 64 + i];
  float o1 = x1 * c - x2 * s;
  float o2 = x1 * s + x2 * c;
  if (head < 32) { o1 *= QK_SCALE; o2 *= QK_SCALE; }
  QKV[base + i]      = (half_t)o1;
  QKV[base + 64 + i] = (half_t)o2;
}

// ---------------- V transpose: QKV V-slice [t][kh*128+d] -> Vt[kh][d][t] ----
__global__ __launch_bounds__(256) void transpose_v_k(const half_t* __restrict__ QKV,
                                                     half_t* __restrict__ Vt) {
  int idx = blockIdx.x * 256 + threadIdx.x;   // 8*128*256 = 262144
  int d  = idx & 127;
  int ts = (idx >> 7) & 255;
  int kh = idx >> 15;
  half8 o;
#pragma unroll
  for (int i = 0; i < 8; ++i)
    o[i] = QKV[(size_t)(ts * 8 + i) * QCOLS + HID + NKV * HD + kh * HD + d];
  *(half8*)&Vt[(size_t)kh * (HD * T_SEQ) + (size_t)d * T_SEQ + ts * 8] = o;
}

// ---------------- fp16 GEMM (R3-verified): 4-phase, 2-buffer, drain/tile ----
// C[M][N] = A[M][K] * B[N][K]^T.  512 thr = 8 waves (2M x 4N), BK=64,
// double-buffered LDS, per-phase {stage || ds_read || MFMA cluster} with raw
// s_barrier; one vmcnt(0)+__syncthreads per K-tile. XOR-(row&7) LDS swizzle
// (both-sides involution: pre-swizzled global source, swizzled ds_read).
template <int BM, int BN, int OUT_HALF>
__global__ __launch_bounds__(512, 2) void gemm8p_k(const half_t* __restrict__ A,
                                                   const half_t* __restrict__ Bm,
                                                   void* __restrict__ Cout,
                                                   int M, int N, int K) {
  constexpr int MF = BM / 32;   // per-wave m fragments
  constexpr int NF = BN / 64;   // per-wave n fragments
  constexpr int MH = MF / 2;    // m frags per phase
  constexpr int LA = BM / 64;   // staging loads/thread for A tile
  constexpr int LB = BN / 64;
  __shared__ half_t Al[2][BM * 64];
  __shared__ half_t Bl[2][BN * 64];

  const int nbm = M / BM;
  const int nwg = nbm * (N / BN);     // 256 for both instantiations
  const int bid = blockIdx.x;
  const int swz = (bid & 7) * (nwg >> 3) + (bid >> 3);  // bijective XCD swizzle
  const int brow = (swz % nbm) * BM;
  const int bcol = (swz / nbm) * BN;
  const int tid = threadIdx.x;
  const int lane = tid & 63, wid = tid >> 6;
  const int wr = wid >> 2, wc = wid & 3;
  const int lr = lane & 15, hi = lane >> 4;
  const int wrow = wr * (MF * 16), wcol = wc * (NF * 16);

  const half_t* Ab = A + (size_t)brow * K;
  const half_t* Bb = Bm + (size_t)bcol * K;

  f32x4 acc[MF][NF] = {};
  half8 afr[MH], bfr[NF];

#define STAGE_A(l, k0, buf) { \
    int c_ = (l) * 512 + tid; int r_ = c_ >> 3, s_ = c_ & 7; \
    __builtin_amdgcn_global_load_lds( \
      (cg_void*)(Ab + (size_t)r_ * K + (k0) + ((s_ ^ (r_ & 7)) * 8)), \
      (lds_void*)(&Al[buf][((l) * 512 + wid * 64) * 8]), 16, 0, 0); }
#define STAGE_B(l, k0, buf) { \
    int c_ = (l) * 512 + tid; int r_ = c_ >> 3, s_ = c_ & 7; \
    __builtin_amdgcn_global_load_lds( \
      (cg_void*)(Bb + (size_t)r_ * K + (k0) + ((s_ ^ (r_ & 7)) * 8)), \
      (lds_void*)(&Bl[buf][((l) * 512 + wid * 64) * 8]), 16, 0, 0); }
#define RD_A(i, mh, kk, buf) { \
    int row_ = wrow + ((mh) * MH + (i)) * 16 + lr; int ks_ = (kk) * 4 + hi; \
    afr[i] = *(const half8*)&Al[buf][row_ * 64 + ((ks_ ^ (row_ & 7)) * 8)]; }
#define RD_B(n, kk, buf) { \
    int row_ = wcol + (n) * 16 + lr; int ks_ = (kk) * 4 + hi; \
    bfr[n] = *(const half8*)&Bl[buf][row_ * 64 + ((ks_ ^ (row_ & 7)) * 8)]; }
#define MFMA_PH(mh) { \
    __builtin_amdgcn_s_setprio(1); \
    _Pragma("unroll") for (int i_ = 0; i_ < MH; ++i_) \
      _Pragma("unroll") for (int n_ = 0; n_ < NF; ++n_) \
        acc[(mh) * MH + i_][n_] = __builtin_amdgcn_mfma_f32_16x16x32_f16( \
            afr[i_], bfr[n_], acc[(mh) * MH + i_][n_], 0, 0, 0); \
    __builtin_amdgcn_s_setprio(0); }

#define DO_TILE(T, BUF) { \
    const int kn_ = ((T) + 1) * 64; const bool pf_ = ((T) + 1) < NT; \
    /* phase 0: mh0,kk0 ; stage next-A */ \
    if (pf_) { _Pragma("unroll") for (int l_ = 0; l_ < LA; ++l_) STAGE_A(l_, kn_, (BUF) ^ 1); } \
    _Pragma("unroll") for (int n_ = 0; n_ < NF; ++n_) RD_B(n_, 0, BUF); \
    _Pragma("unroll") for (int i_ = 0; i_ < MH; ++i_) RD_A(i_, 0, 0, BUF); \
    MFMA_PH(0); \
    __builtin_amdgcn_s_barrier(); __builtin_amdgcn_sched_barrier(0); \
    /* phase 1: mh1,kk0 (reuse bfr) ; stage next-B */ \
    if (pf_) { _Pragma("unroll") for (int l_ = 0; l_ < LB; ++l_) STAGE_B(l_, kn_, (BUF) ^ 1); } \
    _Pragma("unroll") for (int i_ = 0; i_ < MH; ++i_) RD_A(i_, 1, 0, BUF); \
    MFMA_PH(1); \
    __builtin_amdgcn_s_barrier(); __builtin_amdgcn_sched_barrier(0); \
    /* phase 2: mh1,kk1 */ \
    _Pragma("unroll") for (int n_ = 0; n_ < NF; ++n_) RD_B(n_, 1, BUF); \
    _Pragma("unroll") for (int i_ = 0; i_ < MH; ++i_) RD_A(i_, 1, 1, BUF); \
    MFMA_PH(1); \
    __builtin_amdgcn_s_barrier(); __builtin_amdgcn_sched_barrier(0); \
    /* phase 3: mh0,kk1 (reuse bfr) */ \
    _Pragma("unroll") for (int i_ = 0; i_ < MH; ++i_) RD_A(i_, 0, 1, BUF); \
    MFMA_PH(0); \
    asm volatile("s_waitcnt vmcnt(0)" ::: "memory"); \
    __syncthreads(); }

  const int NT = K / 64;
  // prologue: stage tile 0 into buf0, drain, sync
#pragma unroll
  for (int l_ = 0; l_ < LA; ++l_) STAGE_A(l_, 0, 0);
#pragma unroll
  for (int l_ = 0; l_ < LB; ++l_) STAGE_B(l_, 0, 0);
  asm volatile("s_waitcnt vmcnt(0)" ::: "memory");
  __syncthreads();

  for (int t = 0; t < NT; t += 2) {
    DO_TILE(t, 0);
    DO_TILE(t + 1, 1);
  }

#undef STAGE_A
#undef STAGE_B
#undef RD_A
#undef RD_B
#undef MFMA_PH
#undef DO_TILE

#pragma unroll
  for (int m = 0; m < MF; ++m)
#pragma unroll
    for (int n = 0; n < NF; ++n)
#pragma unroll
      for (int r = 0; r < 4; ++r) {
        int row = brow + wrow + m * 16 + hi * 4 + r;
        int col = bcol + wcol + n * 16 + lr;
        float v = acc[m][n][r];
        if (OUT_HALF) ((half_t*)Cout)[(size_t)row * N + col] = (half_t)v;
        else          ((float*)Cout)[(size_t)row * N + col] = v;
      }
}

// ---------------- fused causal GQA flash attention, QBLK=128 ----------------
// 512 blocks = 2/CU co-resident; block pairing (15-k, k) balances per-CU work.
// 4 waves; wave w owns TWO 16-row sub-tiles (rows qb*128 + s*64 + w*16).
// KVBLK=64. One K/V stage + barrier pair feeds 64 MFMA (kf/vf reused across
// both sub-tiles). All LDS reads b128 via both-sides XOR swizzle.
__global__ __launch_bounds__(256, 2) void attn_k(const half_t* __restrict__ QKV,
                                                 const half_t* __restrict__ Vt,
                                                 half_t* __restrict__ Ob) {
  const int bid = blockIdx.x;
  const int qb = (bid < 256) ? (15 - (bid >> 5)) : ((bid - 256) >> 5);
  const int h  = bid & 31;
  const int kh = h >> 2;
  const int tid = threadIdx.x;
  const int lane = tid & 63;
  const int w = tid >> 6;
  const int lr = lane & 15, hi = lane >> 4;
  const int qbase = qb * 128;

  __shared__ half_t Klds[64 * 128];    // [kv][128] swizzled-linear
  __shared__ half_t Vlds[128 * 64];    // [d][kv]   swizzled-linear
  __shared__ half_t Plds[4 * 32 * 72]; // per-wave P, padded rows

  const half_t* Qp  = QKV + h * HD;
  const half_t* Kp  = QKV + HID + kh * HD;
  const half_t* Vtp = Vt + (size_t)kh * (HD * T_SEQ);

  half8 qf[2][4];
#pragma unroll
  for (int s = 0; s < 2; ++s)
#pragma unroll
    for (int kk = 0; kk < 4; ++kk)
      qf[s][kk] = *(const half8*)&Qp[(size_t)(qbase + s * 64 + w * 16 + lr) * QCOLS + kk * 32 + hi * 8];

  f32x4 acc[2][8] = {};
  float mrow[2][4], lrow[2][4];
#pragma unroll
  for (int s = 0; s < 2; ++s)
#pragma unroll
    for (int r = 0; r < 4; ++r) { mrow[s][r] = -1e30f; lrow[s][r] = 0.0f; }

  half_t* Pw = &Plds[w * (32 * 72)];
  const int nt = 2 * qb + 2;
  for (int t = 0; t < nt; ++t) {
    const int kv0 = t * 64;
    // ---- stage K: 64 rows x 16 slots ----
#pragma unroll
    for (int c = 0; c < 4; ++c) {
      int chunk = c * 256 + tid;
      int r = chunk >> 4, s = chunk & 15;
      int cc = (s & 8) | ((s ^ r) & 7);
      __builtin_amdgcn_global_load_lds(
          (cg_void*)(Kp + (size_t)(kv0 + r) * QCOLS + cc * 8),
          (lds_void*)(&Klds[(c * 256 + w * 64) * 8]), 16, 0, 0);
    }
    // ---- stage Vt: 128 rows x 8 slots ----
#pragma unroll
    for (int c = 0; c < 4; ++c) {
      int chunk = c * 256 + tid;
      int r = chunk >> 3, s = chunk & 7;
      int cc = (s ^ r) & 7;
      __builtin_amdgcn_global_load_lds(
          (cg_void*)(Vtp + (size_t)r * T_SEQ + kv0 + cc * 8),
          (lds_void*)(&Vlds[(c * 256 + w * 64) * 8]), 16, 0, 0);
    }
    __syncthreads();

    // ---- S = Q K^T for both sub-tiles (kf reused) ----
    f32x4 sc[2][4] = {};
#pragma unroll
    for (int jt = 0; jt < 4; ++jt)
#pragma unroll
      for (int kk = 0; kk < 4; ++kk) {
        int srow = jt * 16 + lr;
        int sl = kk * 4 + hi;
        int c = (sl & 8) | ((sl ^ srow) & 7);
        half8 kf = *(const half8*)&Klds[srow * 128 + c * 8];
        sc[0][jt] = __builtin_amdgcn_mfma_f32_16x16x32_f16(qf[0][kk], kf, sc[0][jt], 0, 0, 0);
        sc[1][jt] = __builtin_amdgcn_mfma_f32_16x16x32_f16(qf[1][kk], kf, sc[1][jt], 0, 0, 0);
      }

    // ---- causal mask (elementwise exact; only needed once kv crosses qbase) ----
    if (t >= 2 * qb) {
#pragma unroll
      for (int s = 0; s < 2; ++s)
#pragma unroll
        for (int jt = 0; jt < 4; ++jt)
#pragma unroll
          for (int r = 0; r < 4; ++r) {
            int ig = qbase + s * 64 + w * 16 + hi * 4 + r;
            int jg = kv0 + jt * 16 + lr;
            if (jg > ig) sc[s][jt][r] = -1e30f;
          }
    }

    // ---- online softmax per sub-tile ----
#pragma unroll
    for (int s = 0; s < 2; ++s) {
      float mx[4], scl[4], ls[4];
#pragma unroll
      for (int r = 0; r < 4; ++r)
        mx[r] = fmaxf(fmaxf(sc[s][0][r], sc[s][1][r]), fmaxf(sc[s][2][r], sc[s][3][r]));
#pragma unroll
      for (int off = 1; off < 16; off <<= 1)
#pragma unroll
        for (int r = 0; r < 4; ++r)
          mx[r] = fmaxf(mx[r], __shfl_xor(mx[r], off, 64));
#pragma unroll
      for (int r = 0; r < 4; ++r) {
        float mn = fmaxf(mrow[s][r], mx[r]);
        scl[r] = __expf(mrow[s][r] - mn);
        mrow[s][r] = mn;
        ls[r] = 0.0f;
#pragma unroll
        for (int jt = 0; jt < 4; ++jt) {
          sc[s][jt][r] = __expf(sc[s][jt][r] - mn);
          ls[r] += sc[s][jt][r];
        }
      }
#pragma unroll
      for (int off = 1; off < 16; off <<= 1)
#pragma unroll
        for (int r = 0; r < 4; ++r)
          ls[r] += __shfl_xor(ls[r], off, 64);
#pragma unroll
      for (int r = 0; r < 4; ++r) lrow[s][r] = lrow[s][r] * scl[r] + ls[r];
#pragma unroll
      for (int g = 0; g < 8; ++g)
#pragma unroll
        for (int r = 0; r < 4; ++r) acc[s][g][r] *= scl[r];
    }

    // ---- P -> fp16 via per-wave LDS transpose ----
#pragma unroll
    for (int s = 0; s < 2; ++s)
#pragma unroll
      for (int jt = 0; jt < 4; ++jt)
#pragma unroll
        for (int r = 0; r < 4; ++r)
          Pw[(s * 16 + hi * 4 + r) * 72 + jt * 16 + lr] = (half_t)sc[s][jt][r];
    half8 pf[2][2];
#pragma unroll
    for (int s = 0; s < 2; ++s)
#pragma unroll
      for (int jt = 0; jt < 2; ++jt)
        pf[s][jt] = *(const half8*)&Pw[(s * 16 + lr) * 72 + jt * 32 + hi * 8];

    // ---- O += P V (vf reused across sub-tiles) ----
#pragma unroll
    for (int g = 0; g < 8; ++g)
#pragma unroll
      for (int jt = 0; jt < 2; ++jt) {
        int vrow = g * 16 + lr;
        int sl = jt * 4 + hi;
        int c = (sl ^ vrow) & 7;
        half8 vf = *(const half8*)&Vlds[vrow * 64 + c * 8];
        acc[0][g] = __builtin_amdgcn_mfma_f32_16x16x32_f16(pf[0][jt], vf, acc[0][g], 0, 0, 0);
        acc[1][g] = __builtin_amdgcn_mfma_f32_16x16x32_f16(pf[1][jt], vf, acc[1][g], 0, 0, 0);
      }
    __syncthreads();
  }

  // ---- epilogue: O / l ----
#pragma unroll
  for (int s = 0; s < 2; ++s)
#pragma unroll
    for (int g = 0; g < 8; ++g)
#pragma unroll
      for (int r = 0; r < 4; ++r) {
        int row = qbase + s * 64 + w * 16 + hi * 4 + r;
        int col = h * HD + g * 16 + lr;
        Ob[(size_t)row * HID + col] = (half_t)(acc[s][g][r] / lrow[s][r]);
      }
}

// ---------------- launch ----------------
extern "C" void kernel_launch(void* const* d_in, const int* in_sizes, int n_in,
                              void* d_out, int out_size, void* d_ws, size_t ws_size,
                              hipStream_t stream) {
  const float* hs = (const float*)d_in[0];
  const float* Wq = (const float*)d_in[1];
  const float* Wk = (const float*)d_in[2];
  const float* Wv = (const float*)d_in[3];
  const float* Wo = (const float*)d_in[4];
  float* out = (float*)d_out;

  char* ws = (char*)d_ws;
  half_t* Xh    = (half_t*)(ws + 0);           // 16 MB (dead after gemm1)
  half_t* Vt    = (half_t*)(ws + 0);           // 4 MB, reuses Xh region
  half_t* Wqkvh = (half_t*)(ws + 16777216);    // 48 MB [6144][4096]
  half_t* Woh   = (half_t*)(ws + 67108864);    // 32 MB
  half_t* QKV   = (half_t*)(ws + 100663296);   // 24 MB [2048][6144]
  half_t* attnh = (half_t*)(ws + 125829120);   // 16 MB [2048][4096]
  float*  cs    = (float*)(ws + 142606336);    // 1 MB cos|sin tables
  if (ws_size < 143654912ull) return;

  cast_all_k<<<49152, 256, 0, stream>>>(hs, Wq, Wk, Wv, Wo, Xh, Wqkvh, Woh);
  rope_tables_k<<<512, 256, 0, stream>>>(cs);

  gemm8p_k<256, 192, 1><<<256, 512, 0, stream>>>(Xh, Wqkvh, (void*)QKV, 2048, 6144, 4096);
  rope_apply_k<<<20480, 256, 0, stream>>>(QKV, cs);
  transpose_v_k<<<1024, 256, 0, stream>>>(QKV, Vt);
  attn_k<<<512, 256, 0, stream>>>(QKV, Vt, attnh);
  gemm8p_k<128, 256, 0><<<256, 512, 0, stream>>>(attnh, Woh, (void*)out, 2048, 4096, 4096);
}